// Round 12
// baseline (231.759 us; speedup 1.0000x reference)
//
#include <hip/hip_runtime.h>
#include <hip/hip_cooperative_groups.h>
#include <math.h>

namespace cg = cooperative_groups;

#define NXg 512
#define NYg 512
#define NSEG (NXg * NYg)   // 262144 = 2^18
#define CCH 64
#define CAP 16             // total capacity per pillar (first + 15 ext)
#define ECAP 15            // ext slots per pillar
#define SLOTS 4            // points staged in LDS per pillar (k>4 -> global ext)
#define PSTR 5             // LDS point-slot stride
#define PPB 64             // pillars per tile
#define BN_EPS 1e-3f

// grid constants (f32, as in the reference arrays)
#define PCMINX (-51.2f)
#define PCMINY (-51.2f)
#define PCMINZ (-3.0f)
#define PCMAXX (51.2f)
#define PCMAXY (51.2f)
#define PCMAXZ (3.0f)
#define VOXX (0.2f)
#define VOXY (0.2f)
#define VOXZ (6.0f)

// f32-exact reciprocals (XLA fast-math computes (p-min)*(1/voxel) in f32).
#define RECIPX 5.0f
#define RECIPY 5.0f
#define RECIPZ (__uint_as_float(0x3E2AAAABu))   // (float)(1/6.0f)

__device__ __forceinline__ int calc_pid(float x, float y, float z) {
    bool in_range = (x >= PCMINX) && (x < PCMAXX) &&
                    (y >= PCMINY) && (y < PCMAXY) &&
                    (z >= PCMINZ) && (z < PCMAXZ);
    if (!in_range) return -1;
    int cx = (int)floorf((x - PCMINX) * RECIPX);
    int cy = (int)floorf((y - PCMINY) * RECIPY);
    int p = cy * NXg + cx;
    return (p >= 0 && p < NSEG) ? p : -1;
}

__device__ __forceinline__ void bin_body(int i, const float* __restrict__ pts,
                                         unsigned* __restrict__ cnt,
                                         float4* __restrict__ first,
                                         float4* __restrict__ ext, int N) {
    const float* p = pts + (size_t)i * 3;
    float x = p[0], y = p[1], z = p[2];
    int pd = calc_pid(x, y, z);
    if (pd < 0) return;
    int b = i / N;
    int g = b * NSEG + pd;
    unsigned slot = atomicAdd(&cnt[g], 1u);
    float4 e; e.x = x; e.y = y; e.z = z; e.w = 0.0f;
    if (slot == 0) first[g] = e;
    else if (slot < CAP) ext[(size_t)g * ECAP + (slot - 1)] = e;
}

// One 64-pillar output tile: ph1 gather -> ph2 folded PFN -> ph3 coalesced write.
__device__ __forceinline__ void tile_body(
    int gp0, int t, int lane, int wave,
    float* pxs, float* pys, float* pzs, float* mxs, float* mys, float* mzs,
    int* ks, float* tileb,
    const unsigned* __restrict__ cnt, const float4* __restrict__ first,
    const float4* __restrict__ ext,
    float Ac, float Bc, float Cc, float s3, float s4, float s5,
    float s6, float s7, float s8, float shift, float* __restrict__ out) {
    // ---- phase 1: lane-per-pillar; cnt+first independent loads ----
    if (t < PPB) {
        int gp = gp0 + t;
        float4 f0 = first[gp];
        unsigned kc = cnt[gp];
        int k = (kc < CAP) ? (int)kc : CAP;
        ks[t] = k;
        float sx = 0.f, sy = 0.f, sz = 0.f;
        if (k > 0) {
            sx = f0.x; sy = f0.y; sz = f0.z;
            pxs[t * PSTR + 0] = f0.x;
            pys[t * PSTR + 0] = f0.y;
            pzs[t * PSTR + 0] = f0.z;
            const float4* ex = ext + (size_t)gp * ECAP;
            for (int j = 1; j < k; ++j) {   // ~3% of pillars
                float4 e = ex[j - 1];
                if (j < SLOTS) {
                    pxs[t * PSTR + j] = e.x;
                    pys[t * PSTR + j] = e.y;
                    pzs[t * PSTR + j] = e.z;
                }
                sx += e.x; sy += e.y; sz += e.z;
            }
        }
        float fk = (k > 0) ? (float)k : 1.0f;
        mxs[t] = sx / fk; mys[t] = sy / fk; mzs[t] = sz / fk;
    }
    __syncthreads();

    // ---- phase 2: wave-per-pillar, lane = channel, folded PFN ----
    for (int it = 0; it < 16; ++it) {
        int ppl = wave * 16 + it;
        int k = ks[ppl];
        float acc = 0.0f;
        if (k > 0) {
            float mx = mxs[ppl], my = mys[ppl], mz = mzs[ppl];
            int pid = (gp0 + ppl) & (NSEG - 1);
            float ctx = ((float)(pid & (NXg - 1)) + 0.5f) * VOXX + PCMINX;
            float cty = ((float)(pid >> 9) + 0.5f) * VOXY + PCMINY;
            float D = shift;
            D = fmaf(-mx, s3, D); D = fmaf(-my, s4, D); D = fmaf(-mz, s5, D);
            D = fmaf(-ctx, s6, D); D = fmaf(-cty, s7, D);
            int kl = (k < SLOTS) ? k : SLOTS;
            for (int j = 0; j < kl; ++j) {
                float x = pxs[ppl * PSTR + j];
                float y = pys[ppl * PSTR + j];
                float z = pzs[ppl * PSTR + j];
                float cz = floorf((z - PCMINZ) * RECIPZ);
                float ctz = (cz + 0.5f) * VOXZ + PCMINZ;
                float h = fmaf(x, Ac, fmaf(y, Bc, fmaf(z, Cc, fmaf(z - ctz, s8, D))));
                acc += fmaxf(h, 0.0f);
            }
            for (int j = SLOTS; j < k; ++j) {      // ~never taken
                float4 e = ext[(size_t)(gp0 + ppl) * ECAP + (j - 1)];
                float cz = floorf((e.z - PCMINZ) * RECIPZ);
                float ctz = (cz + 0.5f) * VOXZ + PCMINZ;
                float h = fmaf(e.x, Ac, fmaf(e.y, Bc, fmaf(e.z, Cc,
                              fmaf(e.z - ctz, s8, D))));
                acc += fmaxf(h, 0.0f);
            }
            acc /= (float)k;
        }
        tileb[lane * 65 + ppl] = acc;
    }
    __syncthreads();

    // ---- phase 3: coalesced float4 write-out (64 rows x 16 float4) ----
    int b = gp0 >> 18;                 // NSEG = 2^18
    int pbatch = gp0 & (NSEG - 1);
    size_t obase = (size_t)b * CCH * NSEG + (size_t)pbatch;
    for (int jj = 0; jj < 4; ++jj) {
        int idx = jj * 256 + t;
        int c = idx >> 4;              // channel row 0..63
        int q = idx & 15;              // float4 within row
        float4 v;
        v.x = tileb[c * 65 + q * 4 + 0];
        v.y = tileb[c * 65 + q * 4 + 1];
        v.z = tileb[c * 65 + q * 4 + 2];
        v.w = tileb[c * 65 + q * 4 + 3];
        *reinterpret_cast<float4*>(out + obase + (size_t)c * NSEG + q * 4) = v;
    }
}

// ---------- fused cooperative kernel ----------
__global__ void __launch_bounds__(256) fused_all(
    const float* __restrict__ pts, unsigned* __restrict__ cnt,
    float4* __restrict__ first, float4* __restrict__ ext,
    const float* __restrict__ W, const float* __restrict__ gamma,
    const float* __restrict__ beta, const float* __restrict__ rmean,
    const float* __restrict__ rvar, float* __restrict__ out,
    int B, int N, int ntiles) {
    __shared__ float pxs[PPB * PSTR];
    __shared__ float pys[PPB * PSTR];
    __shared__ float pzs[PPB * PSTR];
    __shared__ float mxs[PPB], mys[PPB], mzs[PPB];
    __shared__ int ks[PPB];
    __shared__ float tileb[CCH * 65];

    cg::grid_group grid = cg::this_grid();
    int t = threadIdx.x;
    int lane = t & 63;
    int wave = t >> 6;
    int nthreads = (int)(gridDim.x * 256);
    int gtid = (int)(blockIdx.x * 256 + t);
    int BN = B * NSEG;

    // per-lane channel constants (live across all phases)
    float w0 = W[0 * CCH + lane], w1 = W[1 * CCH + lane], w2 = W[2 * CCH + lane];
    float w3 = W[3 * CCH + lane], w4 = W[4 * CCH + lane], w5 = W[5 * CCH + lane];
    float w6 = W[6 * CCH + lane], w7 = W[7 * CCH + lane], w8 = W[8 * CCH + lane];
    float sc = gamma[lane] * (1.0f / sqrtf(rvar[lane] + BN_EPS));
    float shift = beta[lane] - rmean[lane] * sc;
    float Ac = (w0 + w3 + w6) * sc;
    float Bc = (w1 + w4 + w7) * sc;
    float Cc = (w2 + w5) * sc;
    float s3 = w3 * sc, s4 = w4 * sc, s5 = w5 * sc;
    float s6 = w6 * sc, s7 = w7 * sc, s8 = w8 * sc;

    // phase 0: zero cnt
    for (int i = gtid; i < BN; i += nthreads) cnt[i] = 0u;
    grid.sync();
    // phase 1: bin points
    int tp = B * N;
    for (int i = gtid; i < tp; i += nthreads)
        bin_body(i, pts, cnt, first, ext, N);
    grid.sync();
    // phase 2: output tiles, grid-stride
    for (int ti = (int)blockIdx.x; ti < ntiles; ti += (int)gridDim.x) {
        tile_body(ti * PPB, t, lane, wave, pxs, pys, pzs, mxs, mys, mzs, ks,
                  tileb, cnt, first, ext, Ac, Bc, Cc, s3, s4, s5, s6, s7, s8,
                  shift, out);
        __syncthreads();
    }
}

// ---------- fallback split kernels (r11 path) ----------
__global__ void k1_bin(const float* __restrict__ pts, unsigned* __restrict__ cnt,
                       float4* __restrict__ first, float4* __restrict__ ext,
                       int B, int N) {
    int i = blockIdx.x * blockDim.x + threadIdx.x;
    if (i >= B * N) return;
    bin_body(i, pts, cnt, first, ext, N);
}

__global__ void __launch_bounds__(256) k4_compute(
    const unsigned* __restrict__ cnt, const float4* __restrict__ first,
    const float4* __restrict__ ext,
    const float* __restrict__ W, const float* __restrict__ gamma,
    const float* __restrict__ beta, const float* __restrict__ rmean,
    const float* __restrict__ rvar, float* __restrict__ out) {
    __shared__ float pxs[PPB * PSTR];
    __shared__ float pys[PPB * PSTR];
    __shared__ float pzs[PPB * PSTR];
    __shared__ float mxs[PPB], mys[PPB], mzs[PPB];
    __shared__ int ks[PPB];
    __shared__ float tileb[CCH * 65];

    int t = threadIdx.x;
    int lane = t & 63;
    int wave = t >> 6;

    float w0 = W[0 * CCH + lane], w1 = W[1 * CCH + lane], w2 = W[2 * CCH + lane];
    float w3 = W[3 * CCH + lane], w4 = W[4 * CCH + lane], w5 = W[5 * CCH + lane];
    float w6 = W[6 * CCH + lane], w7 = W[7 * CCH + lane], w8 = W[8 * CCH + lane];
    float sc = gamma[lane] * (1.0f / sqrtf(rvar[lane] + BN_EPS));
    float shift = beta[lane] - rmean[lane] * sc;
    float Ac = (w0 + w3 + w6) * sc;
    float Bc = (w1 + w4 + w7) * sc;
    float Cc = (w2 + w5) * sc;
    float s3 = w3 * sc, s4 = w4 * sc, s5 = w5 * sc;
    float s6 = w6 * sc, s7 = w7 * sc, s8 = w8 * sc;

    tile_body((int)blockIdx.x * PPB, t, lane, wave, pxs, pys, pzs, mxs, mys,
              mzs, ks, tileb, cnt, first, ext, Ac, Bc, Cc, s3, s4, s5, s6, s7,
              s8, shift, out);
}

extern "C" void kernel_launch(void* const* d_in, const int* in_sizes, int n_in,
                              void* d_out, int out_size, void* d_ws, size_t ws_size,
                              hipStream_t stream) {
    const float* points = (const float*)d_in[0];
    const float* W      = (const float*)d_in[1];
    const float* gamma  = (const float*)d_in[2];
    const float* beta   = (const float*)d_in[3];
    const float* rmean  = (const float*)d_in[4];
    const float* rvar   = (const float*)d_in[5];
    float* out = (float*)d_out;

    int B = out_size / (CCH * NSEG);          // 2
    int N = in_sizes[0] / (3 * B);            // 100000
    int BN = B * NSEG;                        // 524288
    int total_pts = B * N;
    int ntiles = BN / PPB;                    // 4096

    // workspace: cnt [BN] u32 (2 MB) + first [BN] float4 (8.4 MB)
    //          + ext [BN*15] float4 (126 MB)
    unsigned* cnt = (unsigned*)d_ws;
    float4* first = (float4*)(cnt + BN);
    float4* ext   = first + BN;

    // cooperative fused path: grid sized for guaranteed co-residency
    int occ = 0;
    hipError_t oe = hipOccupancyMaxActiveBlocksPerMultiprocessor(
        &occ, fused_all, 256, 0);
    bool coop_ok = false;
    if (oe == hipSuccess && occ > 0) {
        int ncu = 256;                         // MI355X
        hipDeviceProp_t prop;
        if (hipGetDeviceProperties(&prop, 0) == hipSuccess)
            ncu = prop.multiProcessorCount;
        int grid = occ * ncu;
        if (grid > ntiles) grid = ntiles;
        void* args[] = {(void*)&points, (void*)&cnt, (void*)&first, (void*)&ext,
                        (void*)&W, (void*)&gamma, (void*)&beta, (void*)&rmean,
                        (void*)&rvar, (void*)&out, (void*)&B, (void*)&N,
                        (void*)&ntiles};
        hipError_t le = hipLaunchCooperativeKernel((const void*)fused_all,
                                                   dim3(grid), dim3(256), args,
                                                   0, stream);
        coop_ok = (le == hipSuccess);
    }

    if (!coop_ok) {
        // fallback: r11 3-dispatch path
        hipMemsetAsync(cnt, 0, (size_t)BN * sizeof(unsigned), stream);
        int blk = 256;
        int grd_pts = (total_pts + blk - 1) / blk;
        k1_bin<<<grd_pts, blk, 0, stream>>>(points, cnt, first, ext, B, N);
        k4_compute<<<ntiles, blk, 0, stream>>>(cnt, first, ext, W, gamma, beta,
                                               rmean, rvar, out);
    }
}

// Round 13
// 56.000 us; speedup vs baseline: 4.1386x; 4.1386x over previous
//
#include <hip/hip_runtime.h>
#include <math.h>

#define NXg 512
#define NYg 512
#define NSEG (NXg * NYg)   // 262144 = 2^18
#define CCH 64
#define CAP 16             // total capacity per pillar (first + 15 ext)
#define ECAP 15            // ext slots per pillar
#define BN_EPS 1e-3f

// grid constants (f32, as in the reference arrays)
#define PCMINX (-51.2f)
#define PCMINY (-51.2f)
#define PCMINZ (-3.0f)
#define PCMAXX (51.2f)
#define PCMAXY (51.2f)
#define PCMAXZ (3.0f)
#define VOXX (0.2f)
#define VOXY (0.2f)
#define VOXZ (6.0f)

// f32-exact reciprocals (XLA fast-math computes (p-min)*(1/voxel) in f32).
#define RECIPX 5.0f
#define RECIPY 5.0f
#define RECIPZ (__uint_as_float(0x3E2AAAABu))   // (float)(1/6.0f)

__device__ __forceinline__ int calc_pid(float x, float y, float z) {
    bool in_range = (x >= PCMINX) && (x < PCMAXX) &&
                    (y >= PCMINY) && (y < PCMAXY) &&
                    (z >= PCMINZ) && (z < PCMAXZ);
    if (!in_range) return -1;
    int cx = (int)floorf((x - PCMINX) * RECIPX);
    int cy = (int)floorf((y - PCMINY) * RECIPY);
    int p = cy * NXg + cx;
    return (p >= 0 && p < NSEG) ? p : -1;
}

// K0: zero cnt + build folded per-channel constant table (12 floats/channel):
// [Ac,Bc,Cc,s8 | s3,s4,s5,s6 | s7,shift,0,0]
__global__ void k0_init(unsigned* __restrict__ cnt, float* __restrict__ cTab,
                        const float* __restrict__ W,
                        const float* __restrict__ gamma,
                        const float* __restrict__ beta,
                        const float* __restrict__ rmean,
                        const float* __restrict__ rvar, int BN) {
    int i = blockIdx.x * blockDim.x + threadIdx.x;
    if (i < BN) cnt[i] = 0u;
    if (blockIdx.x == 0 && threadIdx.x < CCH) {
        int c = threadIdx.x;
        float w0 = W[0 * CCH + c], w1 = W[1 * CCH + c], w2 = W[2 * CCH + c];
        float w3 = W[3 * CCH + c], w4 = W[4 * CCH + c], w5 = W[5 * CCH + c];
        float w6 = W[6 * CCH + c], w7 = W[7 * CCH + c], w8 = W[8 * CCH + c];
        float sc = gamma[c] * (1.0f / sqrtf(rvar[c] + BN_EPS));
        float shift = beta[c] - rmean[c] * sc;
        cTab[c * 12 + 0] = (w0 + w3 + w6) * sc;   // Ac
        cTab[c * 12 + 1] = (w1 + w4 + w7) * sc;   // Bc
        cTab[c * 12 + 2] = (w2 + w5) * sc;        // Cc
        cTab[c * 12 + 3] = w8 * sc;               // s8
        cTab[c * 12 + 4] = w3 * sc;               // s3
        cTab[c * 12 + 5] = w4 * sc;               // s4
        cTab[c * 12 + 6] = w5 * sc;               // s5
        cTab[c * 12 + 7] = w6 * sc;               // s6
        cTab[c * 12 + 8] = w7 * sc;               // s7
        cTab[c * 12 + 9] = shift;                 // shift
        cTab[c * 12 + 10] = 0.0f;
        cTab[c * 12 + 11] = 0.0f;
    }
}

// K1: point 0 of each pillar -> first[gp]; points 1..15 -> ext[gp*15 + slot-1].
__global__ void k1_bin(const float* __restrict__ pts, unsigned* __restrict__ cnt,
                       float4* __restrict__ first, float4* __restrict__ ext,
                       int B, int N) {
    int i = blockIdx.x * blockDim.x + threadIdx.x;
    if (i >= B * N) return;
    const float* p = pts + (size_t)i * 3;
    float x = p[0], y = p[1], z = p[2];
    int pd = calc_pid(x, y, z);
    if (pd < 0) return;
    int b = i / N;
    int g = b * NSEG + pd;
    unsigned slot = atomicAdd(&cnt[g], 1u);
    float4 e; e.x = x; e.y = y; e.z = z; e.w = 0.0f;
    if (slot == 0) first[g] = e;
    else if (slot < CAP) ext[(size_t)g * ECAP + (slot - 1)] = e;
}

__device__ __forceinline__ float zcenter_off(float z) {
    float cz = floorf((z - PCMINZ) * RECIPZ);
    float ctz = (cz + 0.5f) * VOXZ + PCMINZ;
    return z - ctz;
}

// K4: thread = pillar, 256 pillars/block. Coalesced cnt/first gather, points
// in registers (static-indexed), per-channel folded constants via uniform
// (SGPR) loads, 1 KB-contiguous per-channel writes. No LDS, no barriers.
__global__ void __launch_bounds__(256) k4_compute(
    const unsigned* __restrict__ cnt, const float4* __restrict__ first,
    const float4* __restrict__ ext, const float4* __restrict__ cTab4,
    float* __restrict__ out) {
    int t = threadIdx.x;
    int gp = (int)blockIdx.x * 256 + t;

    float4 f0 = first[gp];
    unsigned kc = cnt[gp];
    int k = (kc < CAP) ? (int)kc : CAP;
    const float4* ex = ext + (size_t)gp * ECAP;

    float x0 = 0.f, y0 = 0.f, z0 = 0.f;
    float x1 = 0.f, y1 = 0.f, z1 = 0.f;
    float x2 = 0.f, y2 = 0.f, z2 = 0.f;
    float x3 = 0.f, y3 = 0.f, z3 = 0.f;
    float sx = 0.f, sy = 0.f, sz = 0.f;
    if (k > 0) { x0 = f0.x; y0 = f0.y; z0 = f0.z; sx = x0; sy = y0; sz = z0; }
    if (k > 1) { float4 e = ex[0]; x1 = e.x; y1 = e.y; z1 = e.z;
                 sx += x1; sy += y1; sz += z1; }
    if (k > 2) { float4 e = ex[1]; x2 = e.x; y2 = e.y; z2 = e.z;
                 sx += x2; sy += y2; sz += z2; }
    if (k > 3) { float4 e = ex[2]; x3 = e.x; y3 = e.y; z3 = e.z;
                 sx += x3; sy += y3; sz += z3; }
    for (int j = 4; j < k; ++j) {               // ~19 pillars total
        float4 e = ex[j - 1];
        sx += e.x; sy += e.y; sz += e.z;
    }
    float fk = (k > 0) ? (float)k : 1.0f;
    float mx = sx / fk, my = sy / fk, mz = sz / fk;
    float rk = 1.0f / fk;

    // per-point z-center offsets (static regs; zeros harmless when masked)
    float zc0 = zcenter_off(z0), zc1 = zcenter_off(z1);
    float zc2 = zcenter_off(z2), zc3 = zcenter_off(z3);

    int pid = gp & (NSEG - 1);
    float ctx = ((float)(pid & (NXg - 1)) + 0.5f) * VOXX + PCMINX;
    float cty = ((float)(pid >> 9) + 0.5f) * VOXY + PCMINY;
    size_t ob = (size_t)(gp >> 18) * CCH * NSEG + (size_t)pid;

    for (int c = 0; c < CCH; ++c) {
        float4 q0 = cTab4[c * 3 + 0];   // Ac,Bc,Cc,s8   (uniform -> s_load)
        float4 q1 = cTab4[c * 3 + 1];   // s3,s4,s5,s6
        float4 q2 = cTab4[c * 3 + 2];   // s7,shift,-,-
        float D = q2.y;
        D = fmaf(-mx, q1.x, D); D = fmaf(-my, q1.y, D); D = fmaf(-mz, q1.z, D);
        D = fmaf(-ctx, q1.w, D); D = fmaf(-cty, q2.x, D);
        float a = 0.0f;
        if (k > 0) {
            float h = fmaf(x0, q0.x, fmaf(y0, q0.y, fmaf(z0, q0.z,
                          fmaf(zc0, q0.w, D))));
            a += fmaxf(h, 0.0f);
        }
        if (k > 1) {
            float h = fmaf(x1, q0.x, fmaf(y1, q0.y, fmaf(z1, q0.z,
                          fmaf(zc1, q0.w, D))));
            a += fmaxf(h, 0.0f);
        }
        if (k > 2) {
            float h = fmaf(x2, q0.x, fmaf(y2, q0.y, fmaf(z2, q0.z,
                          fmaf(zc2, q0.w, D))));
            a += fmaxf(h, 0.0f);
        }
        if (k > 3) {
            float h = fmaf(x3, q0.x, fmaf(y3, q0.y, fmaf(z3, q0.z,
                          fmaf(zc3, q0.w, D))));
            a += fmaxf(h, 0.0f);
        }
        for (int j = 4; j < k; ++j) {           // exec-empty for ~all waves
            float4 e = ex[j - 1];
            float zc = zcenter_off(e.z);
            float h = fmaf(e.x, q0.x, fmaf(e.y, q0.y, fmaf(e.z, q0.z,
                          fmaf(zc, q0.w, D))));
            a += fmaxf(h, 0.0f);
        }
        out[ob + (size_t)c * NSEG] = a * rk;
    }
}

extern "C" void kernel_launch(void* const* d_in, const int* in_sizes, int n_in,
                              void* d_out, int out_size, void* d_ws, size_t ws_size,
                              hipStream_t stream) {
    const float* points = (const float*)d_in[0];
    const float* W      = (const float*)d_in[1];
    const float* gamma  = (const float*)d_in[2];
    const float* beta   = (const float*)d_in[3];
    const float* rmean  = (const float*)d_in[4];
    const float* rvar   = (const float*)d_in[5];
    float* out = (float*)d_out;

    int B = out_size / (CCH * NSEG);          // 2
    int N = in_sizes[0] / (3 * B);            // 100000
    int BN = B * NSEG;                        // 524288
    int total_pts = B * N;

    // workspace: cnt [BN] u32 (2 MB) + cTab [64*12] f32 (3 KB, padded to 4 KB)
    //          + first [BN] float4 (8.4 MB) + ext [BN*15] float4 (126 MB)
    unsigned* cnt = (unsigned*)d_ws;
    float* cTab   = (float*)(cnt + BN);
    float4* first = (float4*)(cTab + 1024);
    float4* ext   = first + BN;

    int blk = 256;
    k0_init<<<(BN + blk - 1) / blk, blk, 0, stream>>>(cnt, cTab, W, gamma,
                                                      beta, rmean, rvar, BN);
    int grd_pts = (total_pts + blk - 1) / blk;
    k1_bin<<<grd_pts, blk, 0, stream>>>(points, cnt, first, ext, B, N);
    k4_compute<<<BN / 256, blk, 0, stream>>>(cnt, first, ext,
                                             (const float4*)cTab, out);
}

// Round 14
// 55.030 us; speedup vs baseline: 4.2115x; 1.0176x over previous
//
#include <hip/hip_runtime.h>
#include <math.h>

#define NXg 512
#define NYg 512
#define NSEG (NXg * NYg)   // 262144 = 2^18
#define CCH 64
#define CAP 16             // total capacity per pillar (first + 15 ext)
#define ECAP 15            // ext slots per pillar
#define SLOTS 4            // points staged in LDS per pillar (k>4 -> global ext)
#define PSTR 5             // LDS point-slot stride
#define PPB 64             // pillars per tile
#define TPB 4              // tiles per block (serial, consecutive -> long write runs)
#define BN_EPS 1e-3f

// grid constants (f32, as in the reference arrays)
#define PCMINX (-51.2f)
#define PCMINY (-51.2f)
#define PCMINZ (-3.0f)
#define PCMAXX (51.2f)
#define PCMAXY (51.2f)
#define PCMAXZ (3.0f)
#define VOXX (0.2f)
#define VOXY (0.2f)
#define VOXZ (6.0f)

// f32-exact reciprocals (XLA fast-math computes (p-min)*(1/voxel) in f32).
#define RECIPX 5.0f
#define RECIPY 5.0f
#define RECIPZ (__uint_as_float(0x3E2AAAABu))   // (float)(1/6.0f)

__device__ __forceinline__ int calc_pid(float x, float y, float z) {
    bool in_range = (x >= PCMINX) && (x < PCMAXX) &&
                    (y >= PCMINY) && (y < PCMAXY) &&
                    (z >= PCMINZ) && (z < PCMAXZ);
    if (!in_range) return -1;
    int cx = (int)floorf((x - PCMINX) * RECIPX);
    int cy = (int)floorf((y - PCMINY) * RECIPY);
    int p = cy * NXg + cx;
    return (p >= 0 && p < NSEG) ? p : -1;
}

// K1: point 0 of each pillar -> first[gp]; points 1..15 -> ext[gp*15 + slot-1].
__global__ void k1_bin(const float* __restrict__ pts, unsigned* __restrict__ cnt,
                       float4* __restrict__ first, float4* __restrict__ ext,
                       int B, int N) {
    int i = blockIdx.x * blockDim.x + threadIdx.x;
    if (i >= B * N) return;
    const float* p = pts + (size_t)i * 3;
    float x = p[0], y = p[1], z = p[2];
    int pd = calc_pid(x, y, z);
    if (pd < 0) return;
    int b = i / N;
    int g = b * NSEG + pd;
    unsigned slot = atomicAdd(&cnt[g], 1u);
    float4 e; e.x = x; e.y = y; e.z = z; e.w = 0.0f;
    if (slot == 0) first[g] = e;
    else if (slot < CAP) ext[(size_t)g * ECAP + (slot - 1)] = e;
}

// K4: block = TPB consecutive 64-pillar tiles, processed serially.
// Wave 3 prefetches tile i+1's pillars into double-buffered staging LDS
// while waves 0-2 compute tile i (wave-per-pillar-range, lane = channel).
// Store phase: all 4 waves, coalesced float4, consecutive tiles -> each
// channel-row stream grows 256B -> 1KB sequential per block.
__global__ void __launch_bounds__(256) k4_compute(
    const unsigned* __restrict__ cnt, const float4* __restrict__ first,
    const float4* __restrict__ ext,
    const float* __restrict__ W, const float* __restrict__ gamma,
    const float* __restrict__ beta, const float* __restrict__ rmean,
    const float* __restrict__ rvar, float* __restrict__ out) {
    __shared__ float pxs[2][PPB * PSTR];
    __shared__ float pys[2][PPB * PSTR];
    __shared__ float pzs[2][PPB * PSTR];
    __shared__ float mxs[2][PPB], mys[2][PPB], mzs[2][PPB];
    __shared__ int ks[2][PPB];
    __shared__ float tileb[CCH * 65];

    int t = threadIdx.x;
    int lane = t & 63;
    int wave = t >> 6;
    int tile0 = (int)blockIdx.x * TPB;

    // per-lane channel constants (lane = channel in compute phase)
    float w0 = W[0 * CCH + lane], w1 = W[1 * CCH + lane], w2 = W[2 * CCH + lane];
    float w3 = W[3 * CCH + lane], w4 = W[4 * CCH + lane], w5 = W[5 * CCH + lane];
    float w6 = W[6 * CCH + lane], w7 = W[7 * CCH + lane], w8 = W[8 * CCH + lane];
    float sc = gamma[lane] * (1.0f / sqrtf(rvar[lane] + BN_EPS));
    float shift = beta[lane] - rmean[lane] * sc;
    float Ac = (w0 + w3 + w6) * sc;
    float Bc = (w1 + w4 + w7) * sc;
    float Cc = (w2 + w5) * sc;
    float s3 = w3 * sc, s4 = w4 * sc, s5 = w5 * sc;
    float s6 = w6 * sc, s7 = w7 * sc, s8 = w8 * sc;

    // ---- gather helper (executed by wave 3; gl = lane) ----
    auto gather = [&](int tile, int buf, int gl) {
        int gp = tile * PPB + gl;
        float4 f0 = first[gp];
        unsigned kc = cnt[gp];
        int k = (kc < CAP) ? (int)kc : CAP;
        ks[buf][gl] = k;
        float sx = 0.f, sy = 0.f, sz = 0.f;
        if (k > 0) {
            sx = f0.x; sy = f0.y; sz = f0.z;
            pxs[buf][gl * PSTR + 0] = f0.x;
            pys[buf][gl * PSTR + 0] = f0.y;
            pzs[buf][gl * PSTR + 0] = f0.z;
            const float4* ex = ext + (size_t)gp * ECAP;
            for (int j = 1; j < k; ++j) {   // ~3% of pillars
                float4 e = ex[j - 1];
                if (j < SLOTS) {
                    pxs[buf][gl * PSTR + j] = e.x;
                    pys[buf][gl * PSTR + j] = e.y;
                    pzs[buf][gl * PSTR + j] = e.z;
                }
                sx += e.x; sy += e.y; sz += e.z;
            }
        }
        float fk = (k > 0) ? (float)k : 1.0f;
        mxs[buf][gl] = sx / fk; mys[buf][gl] = sy / fk; mzs[buf][gl] = sz / fk;
    };

    // prologue: wave 3 gathers tile 0 into buf 0
    if (t >= 192) gather(tile0, 0, t - 192);
    __syncthreads();

    for (int i = 0; i < TPB; ++i) {
        int buf = i & 1;
        int gp0 = (tile0 + i) * PPB;

        if (t >= 192) {
            // wave 3: prefetch next tile into the other buffer
            if (i + 1 < TPB) gather(tile0 + i + 1, buf ^ 1, t - 192);
        } else {
            // waves 0-2: compute 64 pillars (22/22/20 split), lane = channel
            int pstart = wave * 22;
            int pend = (wave == 2) ? PPB : pstart + 22;
            for (int ppl = pstart; ppl < pend; ++ppl) {
                int k = ks[buf][ppl];
                float acc = 0.0f;
                if (k > 0) {
                    float mx = mxs[buf][ppl], my = mys[buf][ppl], mz = mzs[buf][ppl];
                    int pid = (gp0 + ppl) & (NSEG - 1);
                    float ctx = ((float)(pid & (NXg - 1)) + 0.5f) * VOXX + PCMINX;
                    float cty = ((float)(pid >> 9) + 0.5f) * VOXY + PCMINY;
                    float D = shift;
                    D = fmaf(-mx, s3, D); D = fmaf(-my, s4, D); D = fmaf(-mz, s5, D);
                    D = fmaf(-ctx, s6, D); D = fmaf(-cty, s7, D);
                    int kl = (k < SLOTS) ? k : SLOTS;
                    for (int j = 0; j < kl; ++j) {
                        float x = pxs[buf][ppl * PSTR + j];
                        float y = pys[buf][ppl * PSTR + j];
                        float z = pzs[buf][ppl * PSTR + j];
                        float cz = floorf((z - PCMINZ) * RECIPZ);
                        float ctz = (cz + 0.5f) * VOXZ + PCMINZ;
                        float h = fmaf(x, Ac, fmaf(y, Bc, fmaf(z, Cc,
                                      fmaf(z - ctz, s8, D))));
                        acc += fmaxf(h, 0.0f);
                    }
                    for (int j = SLOTS; j < k; ++j) {      // ~never taken
                        float4 e = ext[(size_t)(gp0 + ppl) * ECAP + (j - 1)];
                        float cz = floorf((e.z - PCMINZ) * RECIPZ);
                        float ctz = (cz + 0.5f) * VOXZ + PCMINZ;
                        float h = fmaf(e.x, Ac, fmaf(e.y, Bc, fmaf(e.z, Cc,
                                      fmaf(e.z - ctz, s8, D))));
                        acc += fmaxf(h, 0.0f);
                    }
                    acc /= (float)k;
                }
                tileb[lane * 65 + ppl] = acc;
            }
        }
        __syncthreads();

        // ---- store: all 4 waves, coalesced float4 (64 rows x 16 float4) ----
        int b = gp0 >> 18;                 // NSEG = 2^18
        int pbatch = gp0 & (NSEG - 1);
        size_t obase = (size_t)b * CCH * NSEG + (size_t)pbatch;
        for (int jj = 0; jj < 4; ++jj) {
            int idx = jj * 256 + t;
            int c = idx >> 4;              // channel row 0..63
            int q = idx & 15;              // float4 within row
            float4 v;
            v.x = tileb[c * 65 + q * 4 + 0];
            v.y = tileb[c * 65 + q * 4 + 1];
            v.z = tileb[c * 65 + q * 4 + 2];
            v.w = tileb[c * 65 + q * 4 + 3];
            *reinterpret_cast<float4*>(out + obase + (size_t)c * NSEG + q * 4) = v;
        }
        __syncthreads();   // tileb reuse + staging buf handoff
    }
}

extern "C" void kernel_launch(void* const* d_in, const int* in_sizes, int n_in,
                              void* d_out, int out_size, void* d_ws, size_t ws_size,
                              hipStream_t stream) {
    const float* points = (const float*)d_in[0];
    const float* W      = (const float*)d_in[1];
    const float* gamma  = (const float*)d_in[2];
    const float* beta   = (const float*)d_in[3];
    const float* rmean  = (const float*)d_in[4];
    const float* rvar   = (const float*)d_in[5];
    float* out = (float*)d_out;

    int B = out_size / (CCH * NSEG);          // 2
    int N = in_sizes[0] / (3 * B);            // 100000
    int BN = B * NSEG;                        // 524288
    int total_pts = B * N;

    // workspace: cnt [BN] u32 (2 MB) + first [BN] float4 (8.4 MB)
    //          + ext [BN*15] float4 (126 MB)
    unsigned* cnt = (unsigned*)d_ws;
    float4* first = (float4*)(cnt + BN);
    float4* ext   = first + BN;

    hipMemsetAsync(cnt, 0, (size_t)BN * sizeof(unsigned), stream);

    int blk = 256;
    int grd_pts = (total_pts + blk - 1) / blk;
    k1_bin<<<grd_pts, blk, 0, stream>>>(points, cnt, first, ext, B, N);
    int ntiles = BN / PPB;                    // 4096
    k4_compute<<<ntiles / TPB, blk, 0, stream>>>(cnt, first, ext, W, gamma,
                                                 beta, rmean, rvar, out);
}

// Round 15
// 48.784 us; speedup vs baseline: 4.7508x; 1.1280x over previous
//
#include <hip/hip_runtime.h>
#include <math.h>

#define NXg 512
#define NYg 512
#define NSEG (NXg * NYg)   // 262144 = 2^18
#define CCH 64
#define CAP 16             // total capacity per pillar (first + 15 ext)
#define ECAP 15            // ext slots per pillar
#define SLOTS 4            // points staged in LDS per pillar (k>4 -> global ext)
#define PSTR 5             // LDS point-slot stride
#define PPB 64             // pillars per tile
#define BN_EPS 1e-3f

// grid constants (f32, as in the reference arrays)
#define PCMINX (-51.2f)
#define PCMINY (-51.2f)
#define PCMINZ (-3.0f)
#define PCMAXX (51.2f)
#define PCMAXY (51.2f)
#define PCMAXZ (3.0f)
#define VOXX (0.2f)
#define VOXY (0.2f)
#define VOXZ (6.0f)

// f32-exact reciprocals (XLA fast-math computes (p-min)*(1/voxel) in f32).
#define RECIPX 5.0f
#define RECIPY 5.0f
#define RECIPZ (__uint_as_float(0x3E2AAAABu))   // (float)(1/6.0f)

__device__ __forceinline__ int calc_pid(float x, float y, float z) {
    bool in_range = (x >= PCMINX) && (x < PCMAXX) &&
                    (y >= PCMINY) && (y < PCMAXY) &&
                    (z >= PCMINZ) && (z < PCMAXZ);
    if (!in_range) return -1;
    int cx = (int)floorf((x - PCMINX) * RECIPX);
    int cy = (int)floorf((y - PCMINY) * RECIPY);
    int p = cy * NXg + cx;
    return (p >= 0 && p < NSEG) ? p : -1;
}

// K1: point 0 of each pillar -> first[gp]; points 1..15 -> ext[gp*15 + slot-1].
__global__ void k1_bin(const float* __restrict__ pts, unsigned* __restrict__ cnt,
                       float4* __restrict__ first, float4* __restrict__ ext,
                       int B, int N) {
    int i = blockIdx.x * blockDim.x + threadIdx.x;
    if (i >= B * N) return;
    const float* p = pts + (size_t)i * 3;
    float x = p[0], y = p[1], z = p[2];
    int pd = calc_pid(x, y, z);
    if (pd < 0) return;
    int b = i / N;
    int g = b * NSEG + pd;
    unsigned slot = atomicAdd(&cnt[g], 1u);
    float4 e; e.x = x; e.y = y; e.z = z; e.w = 0.0f;
    if (slot == 0) first[g] = e;
    else if (slot < CAP) ext[(size_t)g * ECAP + (slot - 1)] = e;
}

// K4: block = one 64-pillar tile (r11 macro-structure).
// Phase 1 (slot-parallel): wave w loads slot w for all 64 pillars — wave 0:
// first+ks (first issued unconditionally, independent of cnt); waves 1-3:
// ext[w-1] predicated on k>w. Exactly ONE dependent memory hop, no serial
// per-lane ext walk. Phase 2: wave-per-pillar, lane-per-channel folded PFN;
// mean computed redundantly per lane from LDS broadcasts (VALU is idle).
// Phase 3: coalesced float4 canvas write (every output element written).
__global__ void __launch_bounds__(256) k4_compute(
    const unsigned* __restrict__ cnt, const float4* __restrict__ first,
    const float4* __restrict__ ext,
    const float* __restrict__ W, const float* __restrict__ gamma,
    const float* __restrict__ beta, const float* __restrict__ rmean,
    const float* __restrict__ rvar, float* __restrict__ out) {
    __shared__ float pxs[PPB * PSTR];
    __shared__ float pys[PPB * PSTR];
    __shared__ float pzs[PPB * PSTR];
    __shared__ int ks[PPB];
    __shared__ float tileb[CCH * 65];   // [c][p_local]

    int t = threadIdx.x;
    int lane = t & 63;
    int wave = t >> 6;
    int gp0 = (int)blockIdx.x * PPB;

    // per-lane channel constants (lane = channel in phase 2)
    float w0 = W[0 * CCH + lane], w1 = W[1 * CCH + lane], w2 = W[2 * CCH + lane];
    float w3 = W[3 * CCH + lane], w4 = W[4 * CCH + lane], w5 = W[5 * CCH + lane];
    float w6 = W[6 * CCH + lane], w7 = W[7 * CCH + lane], w8 = W[8 * CCH + lane];
    float sc = gamma[lane] * (1.0f / sqrtf(rvar[lane] + BN_EPS));
    float shift = beta[lane] - rmean[lane] * sc;
    float Ac = (w0 + w3 + w6) * sc;
    float Bc = (w1 + w4 + w7) * sc;
    float Cc = (w2 + w5) * sc;
    float s3 = w3 * sc, s4 = w4 * sc, s5 = w5 * sc;
    float s6 = w6 * sc, s7 = w7 * sc, s8 = w8 * sc;

    // ---- phase 1: slot-parallel gather (wave = slot, lane = pillar) ----
    {
        int gp = gp0 + lane;
        unsigned kc = cnt[gp];              // 4x redundant, L1 broadcast
        int k = (kc < CAP) ? (int)kc : CAP;
        if (wave == 0) {
            float4 f0 = first[gp];          // unconditional: independent of cnt
            ks[lane] = k;
            pxs[lane * PSTR + 0] = f0.x;
            pys[lane * PSTR + 0] = f0.y;
            pzs[lane * PSTR + 0] = f0.z;
        } else {
            if (k > wave) {                 // ~3% of lanes active
                float4 e = ext[(size_t)gp * ECAP + (wave - 1)];
                pxs[lane * PSTR + wave] = e.x;
                pys[lane * PSTR + wave] = e.y;
                pzs[lane * PSTR + wave] = e.z;
            }
        }
    }
    __syncthreads();

    // ---- phase 2: wave-per-pillar, lane = channel, folded PFN ----
    for (int it = 0; it < 16; ++it) {
        int ppl = wave * 16 + it;
        int k = ks[ppl];
        float acc = 0.0f;
        if (k > 0) {
            // mean (redundant per lane; LDS broadcast reads, ~free VALU)
            float sx = 0.f, sy = 0.f, sz = 0.f;
            int kl = (k < SLOTS) ? k : SLOTS;
            for (int j = 0; j < kl; ++j) {
                sx += pxs[ppl * PSTR + j];
                sy += pys[ppl * PSTR + j];
                sz += pzs[ppl * PSTR + j];
            }
            for (int j = SLOTS; j < k; ++j) {   // ~19 pillars in the grid
                float4 e = ext[(size_t)(gp0 + ppl) * ECAP + (j - 1)];
                sx += e.x; sy += e.y; sz += e.z;
            }
            float fk = (float)k;
            float rk = 1.0f / fk;               // one div; means via mul
            float mx = sx * rk, my = sy * rk, mz = sz * rk;

            int pid = (gp0 + ppl) & (NSEG - 1);
            float ctx = ((float)(pid & (NXg - 1)) + 0.5f) * VOXX + PCMINX;
            float cty = ((float)(pid >> 9) + 0.5f) * VOXY + PCMINY;
            float D = shift;
            D = fmaf(-mx, s3, D); D = fmaf(-my, s4, D); D = fmaf(-mz, s5, D);
            D = fmaf(-ctx, s6, D); D = fmaf(-cty, s7, D);
            for (int j = 0; j < kl; ++j) {
                float x = pxs[ppl * PSTR + j];
                float y = pys[ppl * PSTR + j];
                float z = pzs[ppl * PSTR + j];
                float cz = floorf((z - PCMINZ) * RECIPZ);
                float ctz = (cz + 0.5f) * VOXZ + PCMINZ;
                float h = fmaf(x, Ac, fmaf(y, Bc, fmaf(z, Cc,
                              fmaf(z - ctz, s8, D))));
                acc += fmaxf(h, 0.0f);
            }
            for (int j = SLOTS; j < k; ++j) {   // ~never taken
                float4 e = ext[(size_t)(gp0 + ppl) * ECAP + (j - 1)];
                float cz = floorf((e.z - PCMINZ) * RECIPZ);
                float ctz = (cz + 0.5f) * VOXZ + PCMINZ;
                float h = fmaf(e.x, Ac, fmaf(e.y, Bc, fmaf(e.z, Cc,
                              fmaf(e.z - ctz, s8, D))));
                acc += fmaxf(h, 0.0f);
            }
            acc *= rk;
        }
        tileb[lane * 65 + ppl] = acc;
    }
    __syncthreads();

    // ---- phase 3: coalesced float4 write-out (64 rows x 16 float4) ----
    int b = gp0 >> 18;                 // NSEG = 2^18
    int pbatch = gp0 & (NSEG - 1);
    size_t obase = (size_t)b * CCH * NSEG + (size_t)pbatch;
    for (int jj = 0; jj < 4; ++jj) {
        int idx = jj * 256 + t;
        int c = idx >> 4;              // channel row 0..63
        int q = idx & 15;              // float4 within row
        float4 v;
        v.x = tileb[c * 65 + q * 4 + 0];
        v.y = tileb[c * 65 + q * 4 + 1];
        v.z = tileb[c * 65 + q * 4 + 2];
        v.w = tileb[c * 65 + q * 4 + 3];
        *reinterpret_cast<float4*>(out + obase + (size_t)c * NSEG + q * 4) = v;
    }
}

extern "C" void kernel_launch(void* const* d_in, const int* in_sizes, int n_in,
                              void* d_out, int out_size, void* d_ws, size_t ws_size,
                              hipStream_t stream) {
    const float* points = (const float*)d_in[0];
    const float* W      = (const float*)d_in[1];
    const float* gamma  = (const float*)d_in[2];
    const float* beta   = (const float*)d_in[3];
    const float* rmean  = (const float*)d_in[4];
    const float* rvar   = (const float*)d_in[5];
    float* out = (float*)d_out;

    int B = out_size / (CCH * NSEG);          // 2
    int N = in_sizes[0] / (3 * B);            // 100000
    int BN = B * NSEG;                        // 524288
    int total_pts = B * N;

    // workspace: cnt [BN] u32 (2 MB) + first [BN] float4 (8.4 MB)
    //          + ext [BN*15] float4 (126 MB)
    unsigned* cnt = (unsigned*)d_ws;
    float4* first = (float4*)(cnt + BN);
    float4* ext   = first + BN;

    hipMemsetAsync(cnt, 0, (size_t)BN * sizeof(unsigned), stream);

    int blk = 256;
    int grd_pts = (total_pts + blk - 1) / blk;
    k1_bin<<<grd_pts, blk, 0, stream>>>(points, cnt, first, ext, B, N);
    k4_compute<<<BN / PPB, blk, 0, stream>>>(cnt, first, ext, W, gamma, beta,
                                             rmean, rvar, out);
}

// Round 16
// 48.478 us; speedup vs baseline: 4.7807x; 1.0063x over previous
//
#include <hip/hip_runtime.h>
#include <math.h>

#define NXg 512
#define NYg 512
#define NSEG (NXg * NYg)   // 262144 = 2^18
#define CCH 64
#define CAP 16             // total capacity per pillar (first + 15 ext)
#define ECAP 15            // ext slots per pillar
#define SLOTS 4            // points staged in LDS per pillar (k>4 -> global ext)
#define PSTR 5             // LDS point-slot stride
#define PPB 64             // pillars per tile
#define NXCD 8
#define BN_EPS 1e-3f

// grid constants (f32, as in the reference arrays)
#define PCMINX (-51.2f)
#define PCMINY (-51.2f)
#define PCMINZ (-3.0f)
#define PCMAXX (51.2f)
#define PCMAXY (51.2f)
#define PCMAXZ (3.0f)
#define VOXX (0.2f)
#define VOXY (0.2f)
#define VOXZ (6.0f)

// f32-exact reciprocals (XLA fast-math computes (p-min)*(1/voxel) in f32).
#define RECIPX 5.0f
#define RECIPY 5.0f
#define RECIPZ (__uint_as_float(0x3E2AAAABu))   // (float)(1/6.0f)

__device__ __forceinline__ int calc_pid(float x, float y, float z) {
    bool in_range = (x >= PCMINX) && (x < PCMAXX) &&
                    (y >= PCMINY) && (y < PCMAXY) &&
                    (z >= PCMINZ) && (z < PCMAXZ);
    if (!in_range) return -1;
    int cx = (int)floorf((x - PCMINX) * RECIPX);
    int cy = (int)floorf((y - PCMINY) * RECIPY);
    int p = cy * NXg + cx;
    return (p >= 0 && p < NSEG) ? p : -1;
}

// K1: point 0 of each pillar -> first[gp]; points 1..15 -> ext[gp*15 + slot-1].
__global__ void k1_bin(const float* __restrict__ pts, unsigned* __restrict__ cnt,
                       float4* __restrict__ first, float4* __restrict__ ext,
                       int B, int N) {
    int i = blockIdx.x * blockDim.x + threadIdx.x;
    if (i >= B * N) return;
    const float* p = pts + (size_t)i * 3;
    float x = p[0], y = p[1], z = p[2];
    int pd = calc_pid(x, y, z);
    if (pd < 0) return;
    int b = i / N;
    int g = b * NSEG + pd;
    unsigned slot = atomicAdd(&cnt[g], 1u);
    float4 e; e.x = x; e.y = y; e.z = z; e.w = 0.0f;
    if (slot == 0) first[g] = e;
    else if (slot < CAP) ext[(size_t)g * ECAP + (slot - 1)] = e;
}

// K4: r11 structure + bijective XCD swizzle (single-variable change).
// Each XCD owns a contiguous 1/8 of pillar space, so co-resident blocks on
// one XCD write ADJACENT 256B chunks of each channel row -> L2 assembles
// sequential runs -> long HBM write bursts instead of 2KB-holed streams.
__global__ void __launch_bounds__(256) k4_compute(
    const unsigned* __restrict__ cnt, const float4* __restrict__ first,
    const float4* __restrict__ ext,
    const float* __restrict__ W, const float* __restrict__ gamma,
    const float* __restrict__ beta, const float* __restrict__ rmean,
    const float* __restrict__ rvar, float* __restrict__ out) {
    __shared__ float pxs[PPB * PSTR];
    __shared__ float pys[PPB * PSTR];
    __shared__ float pzs[PPB * PSTR];
    __shared__ float mxs[PPB], mys[PPB], mzs[PPB];
    __shared__ int ks[PPB];
    __shared__ float tileb[CCH * 65];   // [c][p_local]

    int t = threadIdx.x;
    int lane = t & 63;
    int wave = t >> 6;
    // bijective XCD swizzle: gridDim.x == 4096, % 8 == 0
    int cpx = (int)gridDim.x / NXCD;
    int bid = (int)blockIdx.x;
    int swz = (bid % NXCD) * cpx + bid / NXCD;
    int gp0 = swz * PPB;

    // per-lane channel constants (coalesced, L2-hot)
    float w0 = W[0 * CCH + lane], w1 = W[1 * CCH + lane], w2 = W[2 * CCH + lane];
    float w3 = W[3 * CCH + lane], w4 = W[4 * CCH + lane], w5 = W[5 * CCH + lane];
    float w6 = W[6 * CCH + lane], w7 = W[7 * CCH + lane], w8 = W[8 * CCH + lane];
    float sc = gamma[lane] * (1.0f / sqrtf(rvar[lane] + BN_EPS));
    float shift = beta[lane] - rmean[lane] * sc;
    float Ac = (w0 + w3 + w6) * sc;
    float Bc = (w1 + w4 + w7) * sc;
    float Cc = (w2 + w5) * sc;
    float s3 = w3 * sc, s4 = w4 * sc, s5 = w5 * sc;
    float s6 = w6 * sc, s7 = w7 * sc, s8 = w8 * sc;

    // ---- phase 1: lane-per-pillar; cnt+first independent loads ----
    if (t < PPB) {
        int gp = gp0 + t;
        float4 f0 = first[gp];
        unsigned kc = cnt[gp];
        int k = (kc < CAP) ? (int)kc : CAP;
        ks[t] = k;
        float sx = 0.f, sy = 0.f, sz = 0.f;
        if (k > 0) {
            sx = f0.x; sy = f0.y; sz = f0.z;
            pxs[t * PSTR + 0] = f0.x;
            pys[t * PSTR + 0] = f0.y;
            pzs[t * PSTR + 0] = f0.z;
            const float4* ex = ext + (size_t)gp * ECAP;
            for (int j = 1; j < k; ++j) {   // ~3% of pillars
                float4 e = ex[j - 1];
                if (j < SLOTS) {
                    pxs[t * PSTR + j] = e.x;
                    pys[t * PSTR + j] = e.y;
                    pzs[t * PSTR + j] = e.z;
                }
                sx += e.x; sy += e.y; sz += e.z;
            }
        }
        float fk = (k > 0) ? (float)k : 1.0f;
        mxs[t] = sx / fk; mys[t] = sy / fk; mzs[t] = sz / fk;
    }
    __syncthreads();

    // ---- phase 2: wave-per-pillar, lane = channel, folded PFN ----
    for (int it = 0; it < 16; ++it) {
        int ppl = wave * 16 + it;
        int k = ks[ppl];
        float acc = 0.0f;
        if (k > 0) {
            float mx = mxs[ppl], my = mys[ppl], mz = mzs[ppl];
            int pid = (gp0 + ppl) & (NSEG - 1);
            float ctx = ((float)(pid & (NXg - 1)) + 0.5f) * VOXX + PCMINX;
            float cty = ((float)(pid >> 9) + 0.5f) * VOXY + PCMINY;
            float D = shift;
            D = fmaf(-mx, s3, D); D = fmaf(-my, s4, D); D = fmaf(-mz, s5, D);
            D = fmaf(-ctx, s6, D); D = fmaf(-cty, s7, D);
            int kl = (k < SLOTS) ? k : SLOTS;
            for (int j = 0; j < kl; ++j) {
                float x = pxs[ppl * PSTR + j];
                float y = pys[ppl * PSTR + j];
                float z = pzs[ppl * PSTR + j];
                float cz = floorf((z - PCMINZ) * RECIPZ);
                float ctz = (cz + 0.5f) * VOXZ + PCMINZ;
                float h = fmaf(x, Ac, fmaf(y, Bc, fmaf(z, Cc, fmaf(z - ctz, s8, D))));
                acc += fmaxf(h, 0.0f);
            }
            for (int j = SLOTS; j < k; ++j) {      // ~never taken
                float4 e = ext[(size_t)(gp0 + ppl) * ECAP + (j - 1)];
                float cz = floorf((e.z - PCMINZ) * RECIPZ);
                float ctz = (cz + 0.5f) * VOXZ + PCMINZ;
                float h = fmaf(e.x, Ac, fmaf(e.y, Bc, fmaf(e.z, Cc,
                              fmaf(e.z - ctz, s8, D))));
                acc += fmaxf(h, 0.0f);
            }
            acc /= (float)k;
        }
        tileb[lane * 65 + ppl] = acc;
    }
    __syncthreads();

    // ---- phase 3: coalesced float4 write-out (64 rows x 16 float4) ----
    int b = gp0 >> 18;                 // NSEG = 2^18
    int pbatch = gp0 & (NSEG - 1);
    size_t obase = (size_t)b * CCH * NSEG + (size_t)pbatch;
    for (int jj = 0; jj < 4; ++jj) {
        int idx = jj * 256 + t;
        int c = idx >> 4;              // channel row 0..63
        int q = idx & 15;              // float4 within row
        float4 v;
        v.x = tileb[c * 65 + q * 4 + 0];
        v.y = tileb[c * 65 + q * 4 + 1];
        v.z = tileb[c * 65 + q * 4 + 2];
        v.w = tileb[c * 65 + q * 4 + 3];
        *reinterpret_cast<float4*>(out + obase + (size_t)c * NSEG + q * 4) = v;
    }
}

extern "C" void kernel_launch(void* const* d_in, const int* in_sizes, int n_in,
                              void* d_out, int out_size, void* d_ws, size_t ws_size,
                              hipStream_t stream) {
    const float* points = (const float*)d_in[0];
    const float* W      = (const float*)d_in[1];
    const float* gamma  = (const float*)d_in[2];
    const float* beta   = (const float*)d_in[3];
    const float* rmean  = (const float*)d_in[4];
    const float* rvar   = (const float*)d_in[5];
    float* out = (float*)d_out;

    int B = out_size / (CCH * NSEG);          // 2
    int N = in_sizes[0] / (3 * B);            // 100000
    int BN = B * NSEG;                        // 524288
    int total_pts = B * N;

    // workspace: cnt [BN] u32 (2 MB) + first [BN] float4 (8.4 MB)
    //          + ext [BN*15] float4 (126 MB)
    unsigned* cnt = (unsigned*)d_ws;
    float4* first = (float4*)(cnt + BN);
    float4* ext   = first + BN;

    hipMemsetAsync(cnt, 0, (size_t)BN * sizeof(unsigned), stream);

    int blk = 256;
    int grd_pts = (total_pts + blk - 1) / blk;
    k1_bin<<<grd_pts, blk, 0, stream>>>(points, cnt, first, ext, B, N);
    k4_compute<<<BN / PPB, blk, 0, stream>>>(cnt, first, ext, W, gamma, beta,
                                             rmean, rvar, out);
}

// Round 18
// 47.003 us; speedup vs baseline: 4.9307x; 1.0314x over previous
//
#include <hip/hip_runtime.h>
#include <math.h>

#define NXg 512
#define NYg 512
#define NSEG (NXg * NYg)   // 262144 = 2^18
#define CCH 64
#define CAP 16             // total capacity per pillar (first + 15 ext)
#define ECAP 15            // ext slots per pillar
#define SLOTS 4            // points staged in LDS per pillar (k>4 -> global ext)
#define PSTR 5             // LDS point-slot stride
#define PPB 64             // pillars per tile
#define BN_EPS 1e-3f

// grid constants (f32, as in the reference arrays)
#define PCMINX (-51.2f)
#define PCMINY (-51.2f)
#define PCMINZ (-3.0f)
#define PCMAXX (51.2f)
#define PCMAXY (51.2f)
#define PCMAXZ (3.0f)
#define VOXX (0.2f)
#define VOXY (0.2f)
#define VOXZ (6.0f)

// f32-exact reciprocals (XLA fast-math computes (p-min)*(1/voxel) in f32).
#define RECIPX 5.0f
#define RECIPY 5.0f
#define RECIPZ (__uint_as_float(0x3E2AAAABu))   // (float)(1/6.0f)

// native vector type for nontemporal stores (HIP float4 is a class type,
// which __builtin_nontemporal_store rejects)
typedef float nt_float4 __attribute__((ext_vector_type(4)));

__device__ __forceinline__ int calc_pid(float x, float y, float z) {
    bool in_range = (x >= PCMINX) && (x < PCMAXX) &&
                    (y >= PCMINY) && (y < PCMAXY) &&
                    (z >= PCMINZ) && (z < PCMAXZ);
    if (!in_range) return -1;
    int cx = (int)floorf((x - PCMINX) * RECIPX);
    int cy = (int)floorf((y - PCMINY) * RECIPY);
    int p = cy * NXg + cx;
    return (p >= 0 && p < NSEG) ? p : -1;
}

// K1: point 0 of each pillar -> first[gp]; points 1..15 -> ext[gp*15 + slot-1].
__global__ void k1_bin(const float* __restrict__ pts, unsigned* __restrict__ cnt,
                       float4* __restrict__ first, float4* __restrict__ ext,
                       int B, int N) {
    int i = blockIdx.x * blockDim.x + threadIdx.x;
    if (i >= B * N) return;
    const float* p = pts + (size_t)i * 3;
    float x = p[0], y = p[1], z = p[2];
    int pd = calc_pid(x, y, z);
    if (pd < 0) return;
    int b = i / N;
    int g = b * NSEG + pd;
    unsigned slot = atomicAdd(&cnt[g], 1u);
    float4 e; e.x = x; e.y = y; e.z = z; e.w = 0.0f;
    if (slot == 0) first[g] = e;
    else if (slot < CAP) ext[(size_t)g * ECAP + (slot - 1)] = e;
}

// K4: r11 structure + NONTEMPORAL canvas stores (single-variable change).
// All 64 channel-row destinations of a block are 1MB apart -> same L2 set;
// nt stores bypass L2 allocation and stream toward LLC/HBM, sidestepping
// the 64-streams-into-one-16-way-set thrash.
__global__ void __launch_bounds__(256) k4_compute(
    const unsigned* __restrict__ cnt, const float4* __restrict__ first,
    const float4* __restrict__ ext,
    const float* __restrict__ W, const float* __restrict__ gamma,
    const float* __restrict__ beta, const float* __restrict__ rmean,
    const float* __restrict__ rvar, float* __restrict__ out) {
    __shared__ float pxs[PPB * PSTR];
    __shared__ float pys[PPB * PSTR];
    __shared__ float pzs[PPB * PSTR];
    __shared__ float mxs[PPB], mys[PPB], mzs[PPB];
    __shared__ int ks[PPB];
    __shared__ float tileb[CCH * 65];   // [c][p_local]

    int t = threadIdx.x;
    int lane = t & 63;
    int wave = t >> 6;
    int gp0 = (int)blockIdx.x * PPB;

    // per-lane channel constants (coalesced, L2-hot)
    float w0 = W[0 * CCH + lane], w1 = W[1 * CCH + lane], w2 = W[2 * CCH + lane];
    float w3 = W[3 * CCH + lane], w4 = W[4 * CCH + lane], w5 = W[5 * CCH + lane];
    float w6 = W[6 * CCH + lane], w7 = W[7 * CCH + lane], w8 = W[8 * CCH + lane];
    float sc = gamma[lane] * (1.0f / sqrtf(rvar[lane] + BN_EPS));
    float shift = beta[lane] - rmean[lane] * sc;
    float Ac = (w0 + w3 + w6) * sc;
    float Bc = (w1 + w4 + w7) * sc;
    float Cc = (w2 + w5) * sc;
    float s3 = w3 * sc, s4 = w4 * sc, s5 = w5 * sc;
    float s6 = w6 * sc, s7 = w7 * sc, s8 = w8 * sc;

    // ---- phase 1: lane-per-pillar; cnt+first independent loads ----
    if (t < PPB) {
        int gp = gp0 + t;
        float4 f0 = first[gp];
        unsigned kc = cnt[gp];
        int k = (kc < CAP) ? (int)kc : CAP;
        ks[t] = k;
        float sx = 0.f, sy = 0.f, sz = 0.f;
        if (k > 0) {
            sx = f0.x; sy = f0.y; sz = f0.z;
            pxs[t * PSTR + 0] = f0.x;
            pys[t * PSTR + 0] = f0.y;
            pzs[t * PSTR + 0] = f0.z;
            const float4* ex = ext + (size_t)gp * ECAP;
            for (int j = 1; j < k; ++j) {   // ~3% of pillars
                float4 e = ex[j - 1];
                if (j < SLOTS) {
                    pxs[t * PSTR + j] = e.x;
                    pys[t * PSTR + j] = e.y;
                    pzs[t * PSTR + j] = e.z;
                }
                sx += e.x; sy += e.y; sz += e.z;
            }
        }
        float fk = (k > 0) ? (float)k : 1.0f;
        mxs[t] = sx / fk; mys[t] = sy / fk; mzs[t] = sz / fk;
    }
    __syncthreads();

    // ---- phase 2: wave-per-pillar, lane = channel, folded PFN ----
    for (int it = 0; it < 16; ++it) {
        int ppl = wave * 16 + it;
        int k = ks[ppl];
        float acc = 0.0f;
        if (k > 0) {
            float mx = mxs[ppl], my = mys[ppl], mz = mzs[ppl];
            int pid = (gp0 + ppl) & (NSEG - 1);
            float ctx = ((float)(pid & (NXg - 1)) + 0.5f) * VOXX + PCMINX;
            float cty = ((float)(pid >> 9) + 0.5f) * VOXY + PCMINY;
            float D = shift;
            D = fmaf(-mx, s3, D); D = fmaf(-my, s4, D); D = fmaf(-mz, s5, D);
            D = fmaf(-ctx, s6, D); D = fmaf(-cty, s7, D);
            int kl = (k < SLOTS) ? k : SLOTS;
            for (int j = 0; j < kl; ++j) {
                float x = pxs[ppl * PSTR + j];
                float y = pys[ppl * PSTR + j];
                float z = pzs[ppl * PSTR + j];
                float cz = floorf((z - PCMINZ) * RECIPZ);
                float ctz = (cz + 0.5f) * VOXZ + PCMINZ;
                float h = fmaf(x, Ac, fmaf(y, Bc, fmaf(z, Cc, fmaf(z - ctz, s8, D))));
                acc += fmaxf(h, 0.0f);
            }
            for (int j = SLOTS; j < k; ++j) {      // ~never taken
                float4 e = ext[(size_t)(gp0 + ppl) * ECAP + (j - 1)];
                float cz = floorf((e.z - PCMINZ) * RECIPZ);
                float ctz = (cz + 0.5f) * VOXZ + PCMINZ;
                float h = fmaf(e.x, Ac, fmaf(e.y, Bc, fmaf(e.z, Cc,
                              fmaf(e.z - ctz, s8, D))));
                acc += fmaxf(h, 0.0f);
            }
            acc /= (float)k;
        }
        tileb[lane * 65 + ppl] = acc;
    }
    __syncthreads();

    // ---- phase 3: nontemporal float4 write-out (64 rows x 16 float4) ----
    int b = gp0 >> 18;                 // NSEG = 2^18
    int pbatch = gp0 & (NSEG - 1);
    size_t obase = (size_t)b * CCH * NSEG + (size_t)pbatch;
    for (int jj = 0; jj < 4; ++jj) {
        int idx = jj * 256 + t;
        int c = idx >> 4;              // channel row 0..63
        int q = idx & 15;              // float4 within row
        nt_float4 v;
        v.x = tileb[c * 65 + q * 4 + 0];
        v.y = tileb[c * 65 + q * 4 + 1];
        v.z = tileb[c * 65 + q * 4 + 2];
        v.w = tileb[c * 65 + q * 4 + 3];
        __builtin_nontemporal_store(
            v, reinterpret_cast<nt_float4*>(out + obase + (size_t)c * NSEG + q * 4));
    }
}

extern "C" void kernel_launch(void* const* d_in, const int* in_sizes, int n_in,
                              void* d_out, int out_size, void* d_ws, size_t ws_size,
                              hipStream_t stream) {
    const float* points = (const float*)d_in[0];
    const float* W      = (const float*)d_in[1];
    const float* gamma  = (const float*)d_in[2];
    const float* beta   = (const float*)d_in[3];
    const float* rmean  = (const float*)d_in[4];
    const float* rvar   = (const float*)d_in[5];
    float* out = (float*)d_out;

    int B = out_size / (CCH * NSEG);          // 2
    int N = in_sizes[0] / (3 * B);            // 100000
    int BN = B * NSEG;                        // 524288
    int total_pts = B * N;

    // workspace: cnt [BN] u32 (2 MB) + first [BN] float4 (8.4 MB)
    //          + ext [BN*15] float4 (126 MB)
    unsigned* cnt = (unsigned*)d_ws;
    float4* first = (float4*)(cnt + BN);
    float4* ext   = first + BN;

    (void)hipMemsetAsync(cnt, 0, (size_t)BN * sizeof(unsigned), stream);

    int blk = 256;
    int grd_pts = (total_pts + blk - 1) / blk;
    k1_bin<<<grd_pts, blk, 0, stream>>>(points, cnt, first, ext, B, N);
    k4_compute<<<BN / PPB, blk, 0, stream>>>(cnt, first, ext, W, gamma, beta,
                                             rmean, rvar, out);
}